// Round 1
// baseline (7321.825 us; speedup 1.0000x reference)
//
#include <hip/hip_runtime.h>
#include <hip/hip_bf16.h>
#include <math.h>

#define BB 256
#define SS 128
#define EE 300
#define HH 300
#define G4 1200
#define DD 601
#define DP 608
#define ASZ 5
#define PP 3

static __device__ __forceinline__ float sigf(float x){ return 1.0f/(1.0f+expf(-x)); }

// ---------------- lengths ----------------
__global__ void lengths_kernel(const int* __restrict__ traw, const int* __restrict__ tleft,
                               const int* __restrict__ aidx, int* __restrict__ lens){
  int b = blockIdx.x, tid = threadIdx.x; // 128 threads
  __shared__ int cnt[3];
  if(tid<3) cnt[tid]=0;
  __syncthreads();
  if(traw[b*SS+tid]!=0)  atomicAdd(&cnt[0],1);
  if(tleft[b*SS+tid]!=0) atomicAdd(&cnt[1],1);
  if(tid<ASZ && aidx[b*ASZ+tid]!=0) atomicAdd(&cnt[2],1);
  __syncthreads();
  if(tid==0){ lens[b]=cnt[0]; lens[BB+b]=cnt[1]; lens[2*BB+b]=cnt[2]; }
}

// ---------------- input projection GEMM (fused embedding gather) ----------------
// Xp[m][n] = sum_k emb[idx[m]][k] * w_ih[n][k] + b_ih[n] + b_hh[n],  m in [0,32768), n in [0,1200)
#define BM 64
#define BN 64
#define BK 50
#define BKP 51
__global__ __launch_bounds__(256)
void xproj_gemm(const int* __restrict__ idxrows, const float* __restrict__ emb,
                const float* __restrict__ w_ih, const float* __restrict__ b_ih,
                const float* __restrict__ b_hh, float* __restrict__ Xp){
  __shared__ float As[BM][BKP];
  __shared__ float Bs[BN][BKP];
  int m0 = blockIdx.y*BM;
  int n0 = blockIdx.x*BN;
  int tid = threadIdx.x;
  float acc[4][4] = {};
  for(int k0=0;k0<EE;k0+=BK){
    for(int i=tid;i<BM*BK;i+=256){
      int r=i/BK, kk=i%BK;
      As[r][kk] = emb[(size_t)idxrows[m0+r]*EE + k0+kk];
    }
    for(int i=tid;i<BN*BK;i+=256){
      int r=i/BK, kk=i%BK;
      int n=n0+r;
      Bs[r][kk] = (n<G4) ? w_ih[(size_t)n*EE + k0+kk] : 0.0f;
    }
    __syncthreads();
    int ty=tid>>4, tx=tid&15;
#pragma unroll 10
    for(int k=0;k<BK;++k){
      float a0=As[ty*4+0][k],a1=As[ty*4+1][k],a2=As[ty*4+2][k],a3=As[ty*4+3][k];
      float b0=Bs[tx*4+0][k],b1=Bs[tx*4+1][k],b2=Bs[tx*4+2][k],b3=Bs[tx*4+3][k];
      acc[0][0]+=a0*b0; acc[0][1]+=a0*b1; acc[0][2]+=a0*b2; acc[0][3]+=a0*b3;
      acc[1][0]+=a1*b0; acc[1][1]+=a1*b1; acc[1][2]+=a1*b2; acc[1][3]+=a1*b3;
      acc[2][0]+=a2*b0; acc[2][1]+=a2*b1; acc[2][2]+=a2*b2; acc[2][3]+=a2*b3;
      acc[3][0]+=a3*b0; acc[3][1]+=a3*b1; acc[3][2]+=a3*b2; acc[3][3]+=a3*b3;
    }
    __syncthreads();
  }
  int ty=tid>>4, tx=tid&15;
  for(int i=0;i<4;i++){
    int m=m0+ty*4+i;
    for(int j=0;j<4;j++){
      int n=n0+tx*4+j;
      if(n<G4) Xp[(size_t)m*G4+n] = acc[i][j] + b_ih[n] + b_hh[n];
    }
  }
}

// ---------------- one LSTM timestep (both gate GEMM + pointwise), per direction ----------------
// grid (4 col-tiles, 64 batch-tiles), 320 threads.  Each block: 4 batches x 75 h-cols (300 gate rows).
__global__ __launch_bounds__(320)
void lstm_step(const float* __restrict__ Xp, const float* __restrict__ Whh,
               const float* __restrict__ h_in, float* __restrict__ h_out,
               float* __restrict__ c, float* __restrict__ mem,
               const int* __restrict__ lens, int t, int dir){
  __shared__ float hs[4][HH];
  __shared__ float gs[4][4][75];
  __shared__ int act[4], sx[4];
  int b0 = blockIdx.y*4;
  int hc0 = blockIdx.x*75;
  int tid = threadIdx.x;
  if(tid<4){
    int len = lens[b0+tid];
    act[tid] = (t < len);
    sx[tid]  = dir ? (len-1-t) : t;   // Xp read row AND mem write row (same map for bwd)
  }
  for(int i=tid;i<4*HH;i+=320){
    int b=i/HH, k=i%HH;
    hs[b][k] = h_in[(size_t)(b0+b)*HH + k];
  }
  __syncthreads();
  bool anyact = act[0]||act[1]||act[2]||act[3];
  if(anyact && tid<300){
    int gate = tid/75, hl = tid%75;
    int grow = gate*HH + hc0 + hl;           // row in [0,1200)
    const float4* wr = reinterpret_cast<const float4*>(Whh + (size_t)grow*HH);
    const float4* h0 = reinterpret_cast<const float4*>(&hs[0][0]);
    const float4* h1 = reinterpret_cast<const float4*>(&hs[1][0]);
    const float4* h2 = reinterpret_cast<const float4*>(&hs[2][0]);
    const float4* h3 = reinterpret_cast<const float4*>(&hs[3][0]);
    float a0=0.f,a1=0.f,a2=0.f,a3=0.f;
#pragma unroll 5
    for(int k=0;k<HH/4;k++){
      float4 w = wr[k];
      float4 x0=h0[k]; a0 += w.x*x0.x + w.y*x0.y + w.z*x0.z + w.w*x0.w;
      float4 x1=h1[k]; a1 += w.x*x1.x + w.y*x1.y + w.z*x1.z + w.w*x1.w;
      float4 x2=h2[k]; a2 += w.x*x2.x + w.y*x2.y + w.z*x2.z + w.w*x2.w;
      float4 x3=h3[k]; a3 += w.x*x3.x + w.y*x3.y + w.z*x3.z + w.w*x3.w;
    }
    if(act[0]) a0 += Xp[((size_t)(b0+0)*SS + sx[0])*G4 + grow];
    if(act[1]) a1 += Xp[((size_t)(b0+1)*SS + sx[1])*G4 + grow];
    if(act[2]) a2 += Xp[((size_t)(b0+2)*SS + sx[2])*G4 + grow];
    if(act[3]) a3 += Xp[((size_t)(b0+3)*SS + sx[3])*G4 + grow];
    gs[gate][0][hl]=a0; gs[gate][1][hl]=a1; gs[gate][2][hl]=a2; gs[gate][3][hl]=a3;
  }
  __syncthreads();
  if(tid<75){
    int hcg = hc0 + tid;
    for(int b=0;b<4;b++){
      int bb = b0+b;
      if(act[b]){
        float ig = sigf(gs[0][b][tid]);
        float fg = sigf(gs[1][b][tid]);
        float gg = tanhf(gs[2][b][tid]);
        float og = sigf(gs[3][b][tid]);
        float cn = fg*c[(size_t)bb*HH+hcg] + ig*gg;
        float hn = og*tanhf(cn);
        c[(size_t)bb*HH+hcg] = cn;
        h_out[(size_t)bb*HH+hcg] = hn;
        mem[((size_t)bb*SS + sx[b])*DP + dir*HH + hcg] = hn;
      } else {
        h_out[(size_t)bb*HH+hcg] = hs[b][hcg];
      }
    }
  }
}

// ---------------- location weighting + attention score (fused) ----------------
__global__ void loc_score_kernel(float* __restrict__ mem, const float* __restrict__ att_w,
                                 const int* __restrict__ lens, float* __restrict__ score){
  int bs = blockIdx.x;
  int b = bs/SS, s = bs%SS;
  int tid = threadIdx.x;  // 128
  int len = lens[b], left = lens[BB+b], alen = lens[2*BB+b];
  int a_start = left, a_end = left + alen;
  float uf = (s<a_start) ? (float)(s-a_start) : (s<a_end ? 0.f : (float)(s-a_end+1));
  float lf = (s<a_start) ? (float)(a_start-s) : (s<a_end ? 0.f : (float)(s-a_end+1));
  float w  = 1.f - lf/(float)len;
  float u  = (s<len) ? uf : 0.f;
  // invalid rows are all-zero (memset) -> scaling irrelevant, score 0 naturally
  float partial = 0.f;
  float* row = mem + (size_t)bs*DP;
  if(s < len){
    for(int e=tid;e<600;e+=128){
      float v = row[e]*w;
      row[e] = v;
      partial += v*att_w[e];
    }
  }
  if(tid==0){
    row[600] = u;
    partial += u*att_w[600];
  }
  __shared__ float red[128];
  red[tid]=partial; __syncthreads();
  for(int s2=64;s2>0;s2>>=1){ if(tid<s2) red[tid]+=red[tid+s2]; __syncthreads(); }
  if(tid==0) score[bs]=red[0];
}

// ---------------- softmax over S + i_t = sum_s alpha*mem ----------------
__global__ void softmax_it_kernel(const float* __restrict__ score, const float* __restrict__ mem,
                                  float* __restrict__ i_t){
  int b = blockIdx.x, tid = threadIdx.x; // 128 threads
  __shared__ float sc[SS];
  __shared__ float red[SS];
  float v = score[b*SS+tid];
  red[tid]=v; __syncthreads();
  for(int s2=64;s2>0;s2>>=1){ if(tid<s2) red[tid]=fmaxf(red[tid],red[tid+s2]); __syncthreads(); }
  float m = red[0]; __syncthreads();
  float e = expf(v-m);
  sc[tid]=e; red[tid]=e; __syncthreads();
  for(int s2=64;s2>0;s2>>=1){ if(tid<s2) red[tid]+=red[tid+s2]; __syncthreads(); }
  float inv = 1.f/red[0]; __syncthreads();
  sc[tid] *= inv;
  __syncthreads();
  float acc[5]={0.f,0.f,0.f,0.f,0.f};
  for(int s=0;s<SS;s++){
    float a = sc[s];
    const float* row = mem + ((size_t)b*SS+s)*DP;
#pragma unroll
    for(int q=0;q<5;q++){
      int d = q*128+tid;
      if(d<DD) acc[q] += a*row[d];
    }
  }
#pragma unroll
  for(int q=0;q<5;q++){
    int d = q*128+tid;
    if(d<DD) i_t[(size_t)b*DP+d] = acc[q];
  }
}

// ---------------- gi = i_t @ gru_w_ih^T + gru_b_ih ----------------
__global__ __launch_bounds__(320)
void gi_kernel(const float* __restrict__ i_t, const float* __restrict__ gwih,
               const float* __restrict__ gbih, float* __restrict__ gi){
  int b = blockIdx.x, tid = threadIdx.x; // 320
  __shared__ float it[DD];
  for(int d=tid;d<DD;d+=320) it[d]=i_t[(size_t)b*DP+d];
  __syncthreads();
  for(int n=tid;n<900;n+=320){
    const float* wr = gwih + (size_t)n*DD;
    float s=0.f;
    for(int d=0;d<DD;d++) s += wr[d]*it[d];
    gi[(size_t)b*900+n] = s + gbih[n];
  }
}

// ---------------- 3 GRU hops + dense (fused) ----------------
__global__ __launch_bounds__(320)
void hops_kernel(const float* __restrict__ gi, const float* __restrict__ gwhh,
                 const float* __restrict__ gbhh, const float* __restrict__ dw,
                 const float* __restrict__ db, float* __restrict__ out){
  int b = blockIdx.x, tid = threadIdx.x; // 320
  __shared__ float et_s[HH];
  float gir=0.f,giz=0.f,gin=0.f,bhr=0.f,bhz=0.f,bhn=0.f;
  if(tid<300){
    et_s[tid]=0.f;
    gir = gi[(size_t)b*900+tid];
    giz = gi[(size_t)b*900+300+tid];
    gin = gi[(size_t)b*900+600+tid];
    bhr = gbhh[tid]; bhz = gbhh[300+tid]; bhn = gbhh[600+tid];
  }
  __syncthreads();
  for(int hop=0;hop<3;hop++){
    float etn=0.f;
    if(tid<300){
      const float* wr = gwhh + (size_t)tid*HH;
      const float* wz = gwhh + (size_t)(300+tid)*HH;
      const float* wn = gwhh + (size_t)(600+tid)*HH;
      float ghr=bhr, ghz=bhz, ghn=bhn;
      for(int d=0;d<HH;d++){
        float e = et_s[d];
        ghr += wr[d]*e; ghz += wz[d]*e; ghn += wn[d]*e;
      }
      float r = sigf(gir+ghr);
      float z = sigf(giz+ghz);
      float n = tanhf(gin + r*ghn);
      etn = (1.f-z)*n + z*et_s[tid];
    }
    __syncthreads();
    if(tid<300) et_s[tid]=etn;
    __syncthreads();
  }
  if(tid<192){
    int p = tid/64, lane = tid%64;
    float partial = 0.f;
    for(int e=lane;e<HH;e+=64) partial += et_s[e]*dw[(size_t)p*HH+e];
    for(int off=32;off>0;off>>=1) partial += __shfl_down(partial, off);
    if(lane==0) out[(size_t)b*PP+p] = partial + db[p];
  }
}

extern "C" void kernel_launch(void* const* d_in, const int* in_sizes, int n_in,
                              void* d_out, int out_size, void* d_ws, size_t ws_size,
                              hipStream_t stream){
  (void)in_sizes; (void)n_in; (void)out_size; (void)ws_size;
  const int*   traw  = (const int*)  d_in[0];
  const int*   aidx  = (const int*)  d_in[1];
  const int*   tleft = (const int*)  d_in[2];
  const float* emb   = (const float*)d_in[3];
  const float* wihf  = (const float*)d_in[4];
  const float* whhf  = (const float*)d_in[5];
  const float* bihf  = (const float*)d_in[6];
  const float* bhhf  = (const float*)d_in[7];
  const float* wihb  = (const float*)d_in[8];
  const float* whhb  = (const float*)d_in[9];
  const float* bihb  = (const float*)d_in[10];
  const float* bhhb  = (const float*)d_in[11];
  const float* attw  = (const float*)d_in[12];
  // d_in[13] att_b unused (cancels in softmax)
  const float* gwih  = (const float*)d_in[14];
  const float* gwhh  = (const float*)d_in[15];
  const float* gbih  = (const float*)d_in[16];
  const float* gbhh  = (const float*)d_in[17];
  const float* dw    = (const float*)d_in[18];
  const float* db    = (const float*)d_in[19];
  float* out = (float*)d_out;

  char* ws = (char*)d_ws;
  size_t off = 0;
  auto alloc = [&](size_t bytes)->void*{
    void* p = ws + off;
    off += (bytes + 255) & ~(size_t)255;
    return p;
  };
  int*   lens  = (int*)  alloc(3*BB*sizeof(int));
  float* Xp    = (float*)alloc((size_t)BB*SS*G4*sizeof(float));   // 157 MB, reused f then b
  float* mem   = (float*)alloc((size_t)BB*SS*DP*sizeof(float));   // 80 MB
  float* states= (float*)alloc((size_t)6*BB*HH*sizeof(float));    // hf0,hf1,hb0,hb1,cf,cb
  float* score = (float*)alloc((size_t)BB*SS*sizeof(float));
  float* i_t   = (float*)alloc((size_t)BB*DP*sizeof(float));
  float* gi    = (float*)alloc((size_t)BB*900*sizeof(float));

  const size_t BH = (size_t)BB*HH;
  float* hf0=states, *hf1=states+BH, *hb0=states+2*BH, *hb1=states+3*BH;
  float* cf=states+4*BH, *cb=states+5*BH;

  hipMemsetAsync(mem,    0, (size_t)BB*SS*DP*sizeof(float), stream);
  hipMemsetAsync(states, 0, 6*BH*sizeof(float), stream);

  lengths_kernel<<<BB,128,0,stream>>>(traw, tleft, aidx, lens);

  // forward direction
  xproj_gemm<<<dim3(19,512),256,0,stream>>>(traw, emb, wihf, bihf, bhhf, Xp);
  {
    float* hin=hf0; float* hout=hf1;
    for(int t=0;t<SS;t++){
      lstm_step<<<dim3(4,64),320,0,stream>>>(Xp, whhf, hin, hout, cf, mem, lens, t, 0);
      float* tmp=hin; hin=hout; hout=tmp;
    }
  }
  // backward direction (reuses Xp)
  xproj_gemm<<<dim3(19,512),256,0,stream>>>(traw, emb, wihb, bihb, bhhb, Xp);
  {
    float* hin=hb0; float* hout=hb1;
    for(int t=0;t<SS;t++){
      lstm_step<<<dim3(4,64),320,0,stream>>>(Xp, whhb, hin, hout, cb, mem, lens, t, 1);
      float* tmp=hin; hin=hout; hout=tmp;
    }
  }

  loc_score_kernel<<<BB*SS,128,0,stream>>>(mem, attw, lens, score);
  softmax_it_kernel<<<BB,128,0,stream>>>(score, mem, i_t);
  gi_kernel<<<BB,320,0,stream>>>(i_t, gwih, gbih, gi);
  hops_kernel<<<BB,320,0,stream>>>(gi, gwhh, gbhh, dw, db, out);
}

// Round 2
// 6429.332 us; speedup vs baseline: 1.1388x; 1.1388x over previous
//
#include <hip/hip_runtime.h>
#include <hip/hip_bf16.h>
#include <hip/hip_cooperative_groups.h>
#include <math.h>

namespace cg = cooperative_groups;

#define BB 256
#define SS 128
#define EE 300
#define HH 300
#define G4 1200
#define DD 601
#define DP 608
#define ASZ 5
#define PP 3

typedef __attribute__((ext_vector_type(8))) short bf16x8s;
typedef __attribute__((ext_vector_type(4))) float f32x4;

union V16 { uint4 q; bf16x8s v; ushort u[8]; };

static __device__ __forceinline__ float sigf(float x){ return 1.0f/(1.0f+expf(-x)); }
static __device__ __forceinline__ float bf2f(ushort u){ unsigned int x = ((unsigned int)u)<<16; return __uint_as_float(x); }
static __device__ __forceinline__ ushort f2bf(float f){ __hip_bfloat16 h = __float2bfloat16(f); return *reinterpret_cast<ushort*>(&h); }

// ---------------- lengths ----------------
__global__ void lengths_kernel(const int* __restrict__ traw, const int* __restrict__ tleft,
                               const int* __restrict__ aidx, int* __restrict__ lens){
  int b = blockIdx.x, tid = threadIdx.x; // 128 threads
  __shared__ int cnt[3];
  if(tid<3) cnt[tid]=0;
  __syncthreads();
  if(traw[b*SS+tid]!=0)  atomicAdd(&cnt[0],1);
  if(tleft[b*SS+tid]!=0) atomicAdd(&cnt[1],1);
  if(tid<ASZ && aidx[b*ASZ+tid]!=0) atomicAdd(&cnt[2],1);
  __syncthreads();
  if(tid==0){ lens[b]=cnt[0]; lens[BB+b]=cnt[1]; lens[2*BB+b]=cnt[2]; }
}

// ---------------- weight prep: Whh[1200][300] f32 -> Wn[dir][1280][320] bf16, n'=hl*4+g ----------------
__global__ void wprep_kernel(const float* __restrict__ whhf, const float* __restrict__ whhb,
                             __hip_bfloat16* __restrict__ Wn){
  int np = blockIdx.x;         // 0..1279
  int dir = blockIdx.y;        // 0..1
  int k = threadIdx.x;         // 0..319
  const float* src = dir ? whhb : whhf;
  int hl = np>>2, g = np&3;
  float v = (hl<300 && k<300) ? src[(size_t)(g*300+hl)*300 + k] : 0.0f;
  Wn[((size_t)dir*1280 + np)*320 + k] = __float2bfloat16(v);
}

// ---------------- input projection GEMM (fused embedding gather), bf16 out ----------------
// Xp[m][n] = sum_k emb[idx[m]][k]*w_ih[n][k] + b_ih[n] + b_hh[n]; m in [0,32768), n in [0,1200)
__global__ __launch_bounds__(256)
void xproj_gemm(const int* __restrict__ idxrows, const float* __restrict__ emb,
                const float* __restrict__ w_ih, const float* __restrict__ b_ih,
                const float* __restrict__ b_hh, __hip_bfloat16* __restrict__ Xp){
  __shared__ float AsT[25][132];
  __shared__ float BsT[25][132];
  __shared__ int rowidx[128];
  int m0 = blockIdx.y*128;
  int n0 = blockIdx.x*128;
  int tid = threadIdx.x;
  if(tid<128) rowidx[tid] = idxrows[m0+tid];
  __syncthreads();
  float acc[8][8] = {};
  for(int k0=0;k0<300;k0+=25){
    for(int i=tid;i<3200;i+=256){
      int r = i/25, kk = i - r*25;
      AsT[kk][r] = emb[(size_t)rowidx[r]*EE + k0+kk];
      int n = n0 + r;
      BsT[kk][r] = (n<G4) ? w_ih[(size_t)n*EE + k0+kk] : 0.0f;
    }
    __syncthreads();
    int ty = tid>>4, tx = tid&15;
#pragma unroll
    for(int k=0;k<25;k++){
      float4 a0 = *(float4*)&AsT[k][ty*8];
      float4 a1 = *(float4*)&AsT[k][ty*8+4];
      float4 b0 = *(float4*)&BsT[k][tx*8];
      float4 b1 = *(float4*)&BsT[k][tx*8+4];
      float av[8] = {a0.x,a0.y,a0.z,a0.w,a1.x,a1.y,a1.z,a1.w};
      float bv[8] = {b0.x,b0.y,b0.z,b0.w,b1.x,b1.y,b1.z,b1.w};
#pragma unroll
      for(int i=0;i<8;i++)
#pragma unroll
        for(int j=0;j<8;j++) acc[i][j] += av[i]*bv[j];
    }
    __syncthreads();
  }
  int ty = tid>>4, tx = tid&15;
  if(n0 + tx*8 >= G4) return;
#pragma unroll
  for(int i=0;i<8;i++){
    int m = m0 + ty*8 + i;
    V16 pk;
#pragma unroll
    for(int j=0;j<8;j++){
      int n = n0 + tx*8 + j;
      float val = acc[i][j] + b_ih[n] + b_hh[n];
      pk.u[j] = f2bf(val);
    }
    *reinterpret_cast<uint4*>(&Xp[(size_t)m*G4 + n0 + tx*8]) = pk.q;
  }
}

// ---------------- cooperative fused BiLSTM recurrence (both dirs, 128 steps) ----------------
// grid 256 = dir(2) x nct(8) x mbt(16); block 128 threads (2 waves).
// Block owns: dir, gate-rows n' in [nct*160, nct*160+160) (hl in [nct*40,+40)), batches [mbt*16,+16).
__global__ __launch_bounds__(128)
void lstm_coop(const __hip_bfloat16* __restrict__ Xpf, const __hip_bfloat16* __restrict__ Xpb,
               const __hip_bfloat16* __restrict__ Wn, __hip_bfloat16* __restrict__ hbuf,
               float* __restrict__ cbuf, float* __restrict__ mem, const int* __restrict__ lens){
  __shared__ uint4 Wl4[6400];            // 160 rows x 40 slots (k-xor-swizzled)  102.4KB
  __shared__ uint4 hA4[640];             // 16 rows x 40 slots (swizzled)          10.2KB
  __shared__ float gbuf[160][20];        //                                        12.8KB
  __shared__ unsigned int sXpU[16][4][20]; // staged Xp slices (40 bf16 each)       5.1KB
  __shared__ int acts[16];
  __shared__ int sxs[16];

  cg::grid_group gg = cg::this_grid();

  int bid = blockIdx.x;
  int dir = bid>>7;
  int rem = bid&127;
  int nct = rem>>4;
  int mbt = rem&15;
  int b0 = mbt*16;
  int n0 = nct*160;
  int hc0 = nct*40;
  int tid = threadIdx.x;
  int w = tid>>6;        // wave 0/1
  int l = tid&63;
  int col = l&15;        // shared row index for A(m) and B(n-col)
  int kgrp = l>>4;
  int colx7 = col&7;

  const __hip_bfloat16* Xp_d = dir ? Xpb : Xpf;

  // ---- load W slice into LDS (once) ----
  const uint4* wsrc = reinterpret_cast<const uint4*>(Wn + ((size_t)dir*1280 + n0)*320);
  for(int i=tid;i<6400;i+=128){
    int r = i/40, q = i - r*40;
    Wl4[r*40 + (q ^ (r&7))] = wsrc[i];
  }

  // per-block max active step
  int tMax = 0;
  for(int m=0;m<16;m++){ int L = lens[b0+m]; tMax = L>tMax ? L : tMax; }

  const size_t HSTRIDE = (size_t)2*BB*320;   // elements per h buffer
  __hip_bfloat16* hp = hbuf;                 // prev
  __hip_bfloat16* ho = hbuf + HSTRIDE;       // out
  __syncthreads();

  for(int t=0;t<SS;t++){
    if(t>=tMax){
      // pure copy of our h slice prev->out (40 bf16 = 20 uints per row)
      for(int i=tid;i<320;i+=128){
        int m = i/20, q = i - m*20;
        size_t base = (((size_t)dir*BB + b0+m)*320 + hc0)>>1;  // uint index
        reinterpret_cast<unsigned int*>(ho)[base + q] =
          reinterpret_cast<const unsigned int*>(hp)[base + q];
      }
      gg.sync();
      __hip_bfloat16* tmp = hp; hp = ho; ho = tmp;
      continue;
    }
    // P0: per-batch act/sx
    if(tid<16){
      int L = lens[b0+tid];
      acts[tid] = (t < L);
      sxs[tid]  = dir ? (L-1-t) : t;
    }
    __syncthreads();
    // P1: stage Xp slices (issue early; HBM latency)
    if(tid<64){
      int m = tid>>2, g = tid&3;
      if(acts[m]){
        const unsigned int* src = reinterpret_cast<const unsigned int*>(
            Xp_d + ((size_t)(b0+m)*SS + sxs[m])*G4 + g*300 + hc0);
#pragma unroll
        for(int q=0;q<20;q++) sXpU[m][g][q] = src[q];
      }
    }
    // P2: load h tile into LDS (swizzled)
    {
      const uint4* hsrc = reinterpret_cast<const uint4*>(hp + ((size_t)dir*BB + b0)*320);
      for(int i=tid;i<640;i+=128){
        int m = i/40, q = i - m*40;
        hA4[m*40 + (q ^ (m&7))] = hsrc[i];
      }
    }
    __syncthreads();
    // P3: MFMA — gates[16m x 160n] = h[16 x 320] @ W^T
    f32x4 acc[5];
#pragma unroll
    for(int i=0;i<5;i++){ acc[i].x=0.f; acc[i].y=0.f; acc[i].z=0.f; acc[i].w=0.f; }
#pragma unroll
    for(int kc=0;kc<10;kc++){
      int qa = kc*4 + kgrp;
      V16 ua; ua.q = hA4[col*40 + (qa ^ colx7)];
#pragma unroll
      for(int i=0;i<5;i++){
        V16 ub; ub.q = Wl4[(w*5+i)*640 + col*40 + (qa ^ colx7)];
        acc[i] = __builtin_amdgcn_mfma_f32_16x16x32_bf16(ua.v, ub.v, acc[i], 0, 0, 0);
      }
    }
    // P4: acc -> gbuf  (D: row m = kgrp*4+j, col n = l&15)
#pragma unroll
    for(int i=0;i<5;i++){
      int n_local = (w*5+i)*16 + col;
      *reinterpret_cast<f32x4*>(&gbuf[n_local][kgrp*4]) = acc[i];
    }
    __syncthreads();
    // P5: pointwise LSTM cell for (hl, m) items
    for(int it=0;it<5;it++){
      int item = tid + it*128;     // 0..639
      int hlL = item>>4, m = item&15;
      int hc = hc0 + hlL;
      if(hc >= HH) continue;
      int b = b0 + m;
      size_t hoff = ((size_t)dir*BB + b)*320 + hc;
      if(acts[m]){
        float pre[4];
#pragma unroll
        for(int g=0;g<4;g++){
          unsigned int wrd = sXpU[m][g][hlL>>1];
          ushort bits = (ushort)(wrd >> (16*(hlL&1)));
          pre[g] = gbuf[hlL*4+g][m] + bf2f(bits);
        }
        float ig = sigf(pre[0]);
        float fg = sigf(pre[1]);
        float ggt = tanhf(pre[2]);
        float og = sigf(pre[3]);
        size_t ci = ((size_t)dir*BB + b)*HH + hc;
        float cn = fg*cbuf[ci] + ig*ggt;
        float hn = og*tanhf(cn);
        cbuf[ci] = cn;
        ho[hoff] = __float2bfloat16(hn);
        mem[((size_t)b*SS + sxs[m])*DP + dir*HH + hc] = hn;
      } else {
        // carry h: copy prev bf16 bits (from LDS hA)
        int q = hc>>3, off = hc&7;
        V16 uh; uh.q = hA4[m*40 + (q ^ (m&7))];
        reinterpret_cast<ushort*>(ho)[hoff] = uh.u[off];
      }
    }
    gg.sync();
    __hip_bfloat16* tmp = hp; hp = ho; ho = tmp;
  }
}

// ---------------- location weighting + attention score (fused) ----------------
__global__ void loc_score_kernel(float* __restrict__ mem, const float* __restrict__ att_w,
                                 const int* __restrict__ lens, float* __restrict__ score){
  int bs = blockIdx.x;
  int b = bs/SS, s = bs%SS;
  int tid = threadIdx.x;  // 128
  int len = lens[b], left = lens[BB+b], alen = lens[2*BB+b];
  int a_start = left, a_end = left + alen;
  float uf = (s<a_start) ? (float)(s-a_start) : (s<a_end ? 0.f : (float)(s-a_end+1));
  float lf = (s<a_start) ? (float)(a_start-s) : (s<a_end ? 0.f : (float)(s-a_end+1));
  float w  = 1.f - lf/(float)len;
  float u  = (s<len) ? uf : 0.f;
  float partial = 0.f;
  float* row = mem + (size_t)bs*DP;
  if(s < len){
    for(int e=tid;e<600;e+=128){
      float v = row[e]*w;
      row[e] = v;
      partial += v*att_w[e];
    }
  }
  if(tid==0){
    row[600] = u;
    partial += u*att_w[600];
  }
  __shared__ float red[128];
  red[tid]=partial; __syncthreads();
  for(int s2=64;s2>0;s2>>=1){ if(tid<s2) red[tid]+=red[tid+s2]; __syncthreads(); }
  if(tid==0) score[bs]=red[0];
}

// ---------------- softmax over S + i_t = sum_s alpha*mem ----------------
__global__ void softmax_it_kernel(const float* __restrict__ score, const float* __restrict__ mem,
                                  float* __restrict__ i_t){
  int b = blockIdx.x, tid = threadIdx.x; // 128 threads
  __shared__ float sc[SS];
  __shared__ float red[SS];
  float v = score[b*SS+tid];
  red[tid]=v; __syncthreads();
  for(int s2=64;s2>0;s2>>=1){ if(tid<s2) red[tid]=fmaxf(red[tid],red[tid+s2]); __syncthreads(); }
  float m = red[0]; __syncthreads();
  float e = expf(v-m);
  sc[tid]=e; red[tid]=e; __syncthreads();
  for(int s2=64;s2>0;s2>>=1){ if(tid<s2) red[tid]+=red[tid+s2]; __syncthreads(); }
  float inv = 1.f/red[0]; __syncthreads();
  sc[tid] *= inv;
  __syncthreads();
  float acc[5]={0.f,0.f,0.f,0.f,0.f};
  for(int s=0;s<SS;s++){
    float a = sc[s];
    const float* row = mem + ((size_t)b*SS+s)*DP;
#pragma unroll
    for(int q=0;q<5;q++){
      int d = q*128+tid;
      if(d<DD) acc[q] += a*row[d];
    }
  }
#pragma unroll
  for(int q=0;q<5;q++){
    int d = q*128+tid;
    if(d<DD) i_t[(size_t)b*DP+d] = acc[q];
  }
}

// ---------------- gi = i_t @ gru_w_ih^T + gru_b_ih ----------------
__global__ __launch_bounds__(320)
void gi_kernel(const float* __restrict__ i_t, const float* __restrict__ gwih,
               const float* __restrict__ gbih, float* __restrict__ gi){
  int b = blockIdx.x, tid = threadIdx.x; // 320
  __shared__ float it[DD];
  for(int d=tid;d<DD;d+=320) it[d]=i_t[(size_t)b*DP+d];
  __syncthreads();
  for(int n=tid;n<900;n+=320){
    const float* wr = gwih + (size_t)n*DD;
    float s=0.f;
    for(int d=0;d<DD;d++) s += wr[d]*it[d];
    gi[(size_t)b*900+n] = s + gbih[n];
  }
}

// ---------------- 3 GRU hops + dense (fused) ----------------
__global__ __launch_bounds__(320)
void hops_kernel(const float* __restrict__ gi, const float* __restrict__ gwhh,
                 const float* __restrict__ gbhh, const float* __restrict__ dw,
                 const float* __restrict__ db, float* __restrict__ out){
  int b = blockIdx.x, tid = threadIdx.x; // 320
  __shared__ float et_s[HH];
  float gir=0.f,giz=0.f,gin=0.f,bhr=0.f,bhz=0.f,bhn=0.f;
  if(tid<300){
    et_s[tid]=0.f;
    gir = gi[(size_t)b*900+tid];
    giz = gi[(size_t)b*900+300+tid];
    gin = gi[(size_t)b*900+600+tid];
    bhr = gbhh[tid]; bhz = gbhh[300+tid]; bhn = gbhh[600+tid];
  }
  __syncthreads();
  for(int hop=0;hop<3;hop++){
    float etn=0.f;
    if(tid<300){
      const float* wr = gwhh + (size_t)tid*HH;
      const float* wz = gwhh + (size_t)(300+tid)*HH;
      const float* wn = gwhh + (size_t)(600+tid)*HH;
      float ghr=bhr, ghz=bhz, ghn=bhn;
      for(int d=0;d<HH;d++){
        float e = et_s[d];
        ghr += wr[d]*e; ghz += wz[d]*e; ghn += wn[d]*e;
      }
      float r = sigf(gir+ghr);
      float z = sigf(giz+ghz);
      float n = tanhf(gin + r*ghn);
      etn = (1.f-z)*n + z*et_s[tid];
    }
    __syncthreads();
    if(tid<300) et_s[tid]=etn;
    __syncthreads();
  }
  if(tid<192){
    int p = tid/64, lane = tid%64;
    float partial = 0.f;
    for(int e=lane;e<HH;e+=64) partial += et_s[e]*dw[(size_t)p*HH+e];
    for(int off=32;off>0;off>>=1) partial += __shfl_down(partial, off);
    if(lane==0) out[(size_t)b*PP+p] = partial + db[p];
  }
}

extern "C" void kernel_launch(void* const* d_in, const int* in_sizes, int n_in,
                              void* d_out, int out_size, void* d_ws, size_t ws_size,
                              hipStream_t stream){
  (void)in_sizes; (void)n_in; (void)out_size; (void)ws_size;
  const int*   traw  = (const int*)  d_in[0];
  const int*   aidx  = (const int*)  d_in[1];
  const int*   tleft = (const int*)  d_in[2];
  const float* emb   = (const float*)d_in[3];
  const float* wihf  = (const float*)d_in[4];
  const float* whhf  = (const float*)d_in[5];
  const float* bihf  = (const float*)d_in[6];
  const float* bhhf  = (const float*)d_in[7];
  const float* wihb  = (const float*)d_in[8];
  const float* whhb  = (const float*)d_in[9];
  const float* bihb  = (const float*)d_in[10];
  const float* bhhb  = (const float*)d_in[11];
  const float* attw  = (const float*)d_in[12];
  // d_in[13] att_b unused (cancels in softmax)
  const float* gwih  = (const float*)d_in[14];
  const float* gwhh  = (const float*)d_in[15];
  const float* gbih  = (const float*)d_in[16];
  const float* gbhh  = (const float*)d_in[17];
  const float* dw    = (const float*)d_in[18];
  const float* db    = (const float*)d_in[19];
  float* out = (float*)d_out;

  char* ws = (char*)d_ws;
  size_t off = 0;
  auto alloc = [&](size_t bytes)->void*{
    void* p = ws + off;
    off += (bytes + 255) & ~(size_t)255;
    return p;
  };
  __hip_bfloat16* Xpf = (__hip_bfloat16*)alloc((size_t)BB*SS*G4*2);      // 78.6 MB
  __hip_bfloat16* Xpb = (__hip_bfloat16*)alloc((size_t)BB*SS*G4*2);      // 78.6 MB
  float* mem   = (float*)alloc((size_t)BB*SS*DP*4);                      // 79.7 MB
  __hip_bfloat16* Wn  = (__hip_bfloat16*)alloc((size_t)2*1280*320*2);    // 1.64 MB
  __hip_bfloat16* hbuf= (__hip_bfloat16*)alloc((size_t)2*2*BB*320*2);    // 655 KB (2 dbuf)
  float* cbuf  = (float*)alloc((size_t)2*BB*HH*4);                       // 614 KB
  int*   lens  = (int*)  alloc(3*BB*sizeof(int));
  float* score = (float*)alloc((size_t)BB*SS*4);
  float* i_t   = (float*)alloc((size_t)BB*DP*4);
  float* gi    = (float*)alloc((size_t)BB*900*4);

  hipMemsetAsync(mem,  0, (size_t)BB*SS*DP*4, stream);
  hipMemsetAsync(hbuf, 0, (size_t)2*2*BB*320*2, stream);
  hipMemsetAsync(cbuf, 0, (size_t)2*BB*HH*4, stream);

  lengths_kernel<<<BB,128,0,stream>>>(traw, tleft, aidx, lens);
  wprep_kernel<<<dim3(1280,2),320,0,stream>>>(whhf, whhb, Wn);

  xproj_gemm<<<dim3(10,256),256,0,stream>>>(traw, emb, wihf, bihf, bhhf, Xpf);
  xproj_gemm<<<dim3(10,256),256,0,stream>>>(traw, emb, wihb, bihb, bhhb, Xpb);

  {
    const __hip_bfloat16* a0 = Xpf;
    const __hip_bfloat16* a1 = Xpb;
    const __hip_bfloat16* a2 = Wn;
    __hip_bfloat16* a3 = hbuf;
    float* a4 = cbuf;
    float* a5 = mem;
    const int* a6 = lens;
    void* cargs[] = {&a0,&a1,&a2,&a3,&a4,&a5,&a6};
    hipLaunchCooperativeKernel((const void*)lstm_coop, dim3(256), dim3(128), cargs, 0, stream);
  }

  loc_score_kernel<<<BB*SS,128,0,stream>>>(mem, attw, lens, score);
  softmax_it_kernel<<<BB,128,0,stream>>>(score, mem, i_t);
  gi_kernel<<<BB,320,0,stream>>>(i_t, gwih, gbih, gi);
  hops_kernel<<<BB,320,0,stream>>>(gi, gwhh, gbhh, dw, db, out);
}

// Round 3
// 3549.175 us; speedup vs baseline: 2.0630x; 1.8115x over previous
//
#include <hip/hip_runtime.h>
#include <hip/hip_bf16.h>
#include <math.h>

#define BB 256
#define SS 128
#define EE 300
#define HH 300
#define G4 1200
#define DD 601
#define DP 608
#define ASZ 5
#define PP 3

typedef __attribute__((ext_vector_type(8))) short bf16x8s;
typedef __attribute__((ext_vector_type(4))) float f32x4;

union V16 { uint4 q; bf16x8s v; ushort u[8]; };

static __device__ __forceinline__ float sigf(float x){ return 1.0f/(1.0f+expf(-x)); }
static __device__ __forceinline__ float bf2f(ushort u){ unsigned int x = ((unsigned int)u)<<16; return __uint_as_float(x); }
static __device__ __forceinline__ ushort f2bf(float f){ __hip_bfloat16 h = __float2bfloat16(f); return *reinterpret_cast<ushort*>(&h); }

// ---------------- lengths ----------------
__global__ void lengths_kernel(const int* __restrict__ traw, const int* __restrict__ tleft,
                               const int* __restrict__ aidx, int* __restrict__ lens){
  int b = blockIdx.x, tid = threadIdx.x; // 128 threads
  __shared__ int cnt[3];
  if(tid<3) cnt[tid]=0;
  __syncthreads();
  if(traw[b*SS+tid]!=0)  atomicAdd(&cnt[0],1);
  if(tleft[b*SS+tid]!=0) atomicAdd(&cnt[1],1);
  if(tid<ASZ && aidx[b*ASZ+tid]!=0) atomicAdd(&cnt[2],1);
  __syncthreads();
  if(tid==0){ lens[b]=cnt[0]; lens[BB+b]=cnt[1]; lens[2*BB+b]=cnt[2]; }
}

// ---------------- weight prep: Whh[1200][300] f32 -> Wn[dir][1280][320] bf16, n'=hl*4+g ----------------
__global__ void wprep_kernel(const float* __restrict__ whhf, const float* __restrict__ whhb,
                             __hip_bfloat16* __restrict__ Wn){
  int np = blockIdx.x;         // 0..1279
  int dir = blockIdx.y;        // 0..1
  int k = threadIdx.x;         // 0..319
  const float* src = dir ? whhb : whhf;
  int hl = np>>2, g = np&3;
  float v = (hl<300 && k<300) ? src[(size_t)(g*300+hl)*300 + k] : 0.0f;
  Wn[((size_t)dir*1280 + np)*320 + k] = __float2bfloat16(v);
}

// ---------------- input projection GEMM via MFMA (fused embedding gather), bf16 out ----------------
// Xp[m][n'] = sum_k emb[idx[m]][k]*w_ih[orig(n')][k] + b_ih + b_hh ; n' = hl*4+g, orig = g*300+hl
// tile 128m x 128n', K chunks of 64 (5 chunks, zero-pad k>=300). 512 threads = 8 waves (4m x 2n).
__global__ __launch_bounds__(512)
void xproj_mfma(const int* __restrict__ idxrows, const float* __restrict__ emb,
                const float* __restrict__ w_ih, const float* __restrict__ b_ih,
                const float* __restrict__ b_hh, __hip_bfloat16* __restrict__ Xp){
  __shared__ uint4 As16[128*8];
  __shared__ uint4 Bs16[128*8];
  __shared__ int rowidx[128];
  int m0 = blockIdx.y*128;
  int n0 = blockIdx.x*128;      // n' base
  int tid = threadIdx.x;
  int w = tid>>6, l = tid&63;
  int col = l&15, kgrp = l>>4;
  int wm = w>>1, wn = w&1;
  if(tid<128) rowidx[tid] = idxrows[m0+tid];
  f32x4 acc[2][4];
#pragma unroll
  for(int a=0;a<2;a++)
#pragma unroll
    for(int bq=0;bq<4;bq++){ acc[a][bq].x=0.f; acc[a][bq].y=0.f; acc[a][bq].z=0.f; acc[a][bq].w=0.f; }
  __syncthreads();  // rowidx ready
  for(int c=0;c<5;c++){
    int k0 = c*64;
    if(c>0) __syncthreads();
#pragma unroll
    for(int j=0;j<2;j++){
      int s = tid*2 + j;               // 0..1023
      int row = s>>3, q = s&7;
      int kb = k0 + q*8;
      // ---- A slot ----
      const float* ar = emb + (size_t)rowidx[row]*EE;
      V16 pk;
      if(kb+7 < 300){
        float4 f0 = *(const float4*)(ar+kb);
        float4 f1 = *(const float4*)(ar+kb+4);
        pk.u[0]=f2bf(f0.x); pk.u[1]=f2bf(f0.y); pk.u[2]=f2bf(f0.z); pk.u[3]=f2bf(f0.w);
        pk.u[4]=f2bf(f1.x); pk.u[5]=f2bf(f1.y); pk.u[6]=f2bf(f1.z); pk.u[7]=f2bf(f1.w);
      } else {
#pragma unroll
        for(int e=0;e<8;e++){ float v = (kb+e<300) ? ar[kb+e] : 0.0f; pk.u[e]=f2bf(v); }
      }
      As16[row*8 + (q^(row&7))] = pk.q;
      // ---- B slot (permuted W row) ----
      int np = n0 + row;
      V16 pb;
      if(np < G4){
        const float* br = w_ih + (size_t)((np&3)*300 + (np>>2))*EE;
        if(kb+7 < 300){
          float4 f0 = *(const float4*)(br+kb);
          float4 f1 = *(const float4*)(br+kb+4);
          pb.u[0]=f2bf(f0.x); pb.u[1]=f2bf(f0.y); pb.u[2]=f2bf(f0.z); pb.u[3]=f2bf(f0.w);
          pb.u[4]=f2bf(f1.x); pb.u[5]=f2bf(f1.y); pb.u[6]=f2bf(f1.z); pb.u[7]=f2bf(f1.w);
        } else {
#pragma unroll
          for(int e=0;e<8;e++){ float v = (kb+e<300) ? br[kb+e] : 0.0f; pb.u[e]=f2bf(v); }
        }
      } else {
        pb.q = make_uint4(0,0,0,0);
      }
      Bs16[row*8 + (q^(row&7))] = pb.q;
    }
    __syncthreads();
#pragma unroll
    for(int kc=0;kc<2;kc++){
      int q = kc*4 + kgrp;
      V16 ua0, ua1, ub0, ub1, ub2, ub3;
      int ra0 = wm*32 + col, ra1 = wm*32 + 16 + col;
      ua0.q = As16[ra0*8 + (q^(ra0&7))];
      ua1.q = As16[ra1*8 + (q^(ra1&7))];
      int rb0 = wn*64 + col;
      ub0.q = Bs16[rb0*8 + (q^(rb0&7))];
      ub1.q = Bs16[(rb0+16)*8 + (q^((rb0+16)&7))];
      ub2.q = Bs16[(rb0+32)*8 + (q^((rb0+32)&7))];
      ub3.q = Bs16[(rb0+48)*8 + (q^((rb0+48)&7))];
      acc[0][0] = __builtin_amdgcn_mfma_f32_16x16x32_bf16(ua0.v, ub0.v, acc[0][0], 0,0,0);
      acc[1][0] = __builtin_amdgcn_mfma_f32_16x16x32_bf16(ua1.v, ub0.v, acc[1][0], 0,0,0);
      acc[0][1] = __builtin_amdgcn_mfma_f32_16x16x32_bf16(ua0.v, ub1.v, acc[0][1], 0,0,0);
      acc[1][1] = __builtin_amdgcn_mfma_f32_16x16x32_bf16(ua1.v, ub1.v, acc[1][1], 0,0,0);
      acc[0][2] = __builtin_amdgcn_mfma_f32_16x16x32_bf16(ua0.v, ub2.v, acc[0][2], 0,0,0);
      acc[1][2] = __builtin_amdgcn_mfma_f32_16x16x32_bf16(ua1.v, ub2.v, acc[1][2], 0,0,0);
      acc[0][3] = __builtin_amdgcn_mfma_f32_16x16x32_bf16(ua0.v, ub3.v, acc[0][3], 0,0,0);
      acc[1][3] = __builtin_amdgcn_mfma_f32_16x16x32_bf16(ua1.v, ub3.v, acc[1][3], 0,0,0);
    }
  }
  // epilogue: D row = kgrp*4+r, col = l&15 within each 16x16 tile
#pragma unroll
  for(int in=0;in<4;in++){
    int np = n0 + wn*64 + in*16 + col;
    if(np >= G4) continue;
    int orig = (np&3)*300 + (np>>2);
    float bias = b_ih[orig] + b_hh[orig];
#pragma unroll
    for(int im=0;im<2;im++){
#pragma unroll
      for(int r=0;r<4;r++){
        int m = m0 + wm*32 + im*16 + kgrp*4 + r;
        float v = acc[im][in][r] + bias;
        Xp[(size_t)m*G4 + np] = __float2bfloat16(v);
      }
    }
  }
}

// ---------------- self-contained BiLSTM recurrence: 32 independent blocks ----------------
// block = (dir, 16-batch group). h (bf16) + c (f32) live in LDS; W streamed from L2 each step.
// 512 threads = 8 waves; wave w owns n' in [w*160, w*160+160) = 10 MFMA n-tiles; M=16 batches.
__global__ __launch_bounds__(512,2)
void lstm_self(const __hip_bfloat16* __restrict__ Xp, const __hip_bfloat16* __restrict__ Wn,
               float* __restrict__ mem, const int* __restrict__ lens){
  __shared__ uint4 hA4[640];          // 16 batches x 40 slots of 8 bf16, XOR-swizzled   10.2KB
  __shared__ float gbuf[16][1296];    // gates [m][n'] (pad 1296)                        82.9KB
  __shared__ float c_s[16][304];      // cell state                                      19.5KB
  int bid = blockIdx.x;               // 32 blocks
  int dir = bid>>4, mbt = bid&15;
  int b0 = mbt*16;
  int tid = threadIdx.x;
  int w = tid>>6, l = tid&63;
  int col = l&15, kgrp = l>>4, colx7 = col&7;
  int pm = tid>>5;                    // pointwise batch 0..15
  int pl = tid&31;                    // pointwise hl lane: hl = pl + 32*j
  int Lm = lens[b0+pm];

  for(int i=tid;i<640;i+=512) hA4[i] = make_uint4(0,0,0,0);
  for(int i=tid;i<16*304;i+=512) ((float*)c_s)[i] = 0.0f;

  int tMax = 0;
  for(int m=0;m<16;m++){ int L = lens[b0+m]; tMax = L>tMax ? L : tMax; }

  const __hip_bfloat16* Xpd = Xp + (size_t)dir*BB*SS*G4;
  const uint4* wp = reinterpret_cast<const uint4*>(Wn + ((size_t)dir*1280 + w*160)*320);
  __syncthreads();

  for(int t=0;t<tMax;++t){
    bool act = (t < Lm);
    int sx = dir ? (Lm-1-t) : t;
    // prefetch Xp gate quads (n'-interleaved: uint2 = 4 bf16 = gates i,f,g,o at hl)
    uint2 xpr[10];
    if(act){
      const uint2* xs = reinterpret_cast<const uint2*>(Xpd + ((size_t)(b0+pm)*SS + sx)*G4) + pl;
#pragma unroll
      for(int j=0;j<10;j++){ if(pl + 32*j < 300) xpr[j] = xs[32*j]; }
    }
    __syncthreads();   // prev pointwise h-writes & gbuf reads complete
    // gates[16m x 1280n'] = h[16x320] @ Wn^T  (B-frags streamed from L2)
    f32x4 acc[10];
#pragma unroll
    for(int i=0;i<10;i++){ acc[i].x=0.f; acc[i].y=0.f; acc[i].z=0.f; acc[i].w=0.f; }
#pragma unroll
    for(int kc=0;kc<10;kc++){
      V16 ua; ua.q = hA4[col*40 + ((kc*4+kgrp) ^ colx7)];
#pragma unroll
      for(int i=0;i<10;i++){
        V16 ub; ub.q = wp[(i*16+col)*40 + kc*4 + kgrp];
        acc[i] = __builtin_amdgcn_mfma_f32_16x16x32_bf16(ua.v, ub.v, acc[i], 0,0,0);
      }
    }
    // D -> gbuf[m][n']  (row = kgrp*4+r, col n' = w*160+i*16+(l&15))
#pragma unroll
    for(int i=0;i<10;i++){
      int np = w*160 + i*16 + col;
#pragma unroll
      for(int r=0;r<4;r++) gbuf[kgrp*4+r][np] = acc[i][r];
    }
    __syncthreads();   // gbuf ready
    // pointwise LSTM cell
    if(act){
#pragma unroll
      for(int j=0;j<10;j++){
        int hl = pl + 32*j;
        if(hl >= 300) continue;
        f32x4 g4 = *reinterpret_cast<const f32x4*>(&gbuf[pm][hl*4]);
        union{ uint2 u2; ushort s[4]; } xv; xv.u2 = xpr[j];
        float ig = sigf(g4.x + bf2f(xv.s[0]));
        float fg = sigf(g4.y + bf2f(xv.s[1]));
        float gg = tanhf(g4.z + bf2f(xv.s[2]));
        float og = sigf(g4.w + bf2f(xv.s[3]));
        float cn = fg*c_s[pm][hl] + ig*gg;
        float hn = og*tanhf(cn);
        c_s[pm][hl] = cn;
        mem[((size_t)(b0+pm)*SS + sx)*DP + dir*HH + hl] = hn;
        int q = hl>>3, e = hl&7;
        reinterpret_cast<ushort*>(&hA4[pm*40 + (q ^ (pm&7))])[e] = f2bf(hn);
      }
    }
  }
}

// ---------------- location weighting + attention score (fused) ----------------
__global__ void loc_score_kernel(float* __restrict__ mem, const float* __restrict__ att_w,
                                 const int* __restrict__ lens, float* __restrict__ score){
  int bs = blockIdx.x;
  int b = bs/SS, s = bs%SS;
  int tid = threadIdx.x;  // 128
  int len = lens[b], left = lens[BB+b], alen = lens[2*BB+b];
  int a_start = left, a_end = left + alen;
  float uf = (s<a_start) ? (float)(s-a_start) : (s<a_end ? 0.f : (float)(s-a_end+1));
  float lf = (s<a_start) ? (float)(a_start-s) : (s<a_end ? 0.f : (float)(s-a_end+1));
  float w  = 1.f - lf/(float)len;
  float u  = (s<len) ? uf : 0.f;
  float partial = 0.f;
  float* row = mem + (size_t)bs*DP;
  if(s < len){
    for(int e=tid;e<600;e+=128){
      float v = row[e]*w;
      row[e] = v;
      partial += v*att_w[e];
    }
  }
  if(tid==0){
    row[600] = u;
    partial += u*att_w[600];
  }
  __shared__ float red[128];
  red[tid]=partial; __syncthreads();
  for(int s2=64;s2>0;s2>>=1){ if(tid<s2) red[tid]+=red[tid+s2]; __syncthreads(); }
  if(tid==0) score[bs]=red[0];
}

// ---------------- softmax over S + i_t = sum_s alpha*mem ----------------
__global__ void softmax_it_kernel(const float* __restrict__ score, const float* __restrict__ mem,
                                  float* __restrict__ i_t){
  int b = blockIdx.x, tid = threadIdx.x; // 128 threads
  __shared__ float sc[SS];
  __shared__ float red[SS];
  float v = score[b*SS+tid];
  red[tid]=v; __syncthreads();
  for(int s2=64;s2>0;s2>>=1){ if(tid<s2) red[tid]=fmaxf(red[tid],red[tid+s2]); __syncthreads(); }
  float m = red[0]; __syncthreads();
  float e = expf(v-m);
  sc[tid]=e; red[tid]=e; __syncthreads();
  for(int s2=64;s2>0;s2>>=1){ if(tid<s2) red[tid]+=red[tid+s2]; __syncthreads(); }
  float inv = 1.f/red[0]; __syncthreads();
  sc[tid] *= inv;
  __syncthreads();
  float acc[5]={0.f,0.f,0.f,0.f,0.f};
  for(int s=0;s<SS;s++){
    float a = sc[s];
    const float* row = mem + ((size_t)b*SS+s)*DP;
#pragma unroll
    for(int q=0;q<5;q++){
      int d = q*128+tid;
      if(d<DD) acc[q] += a*row[d];
    }
  }
#pragma unroll
  for(int q=0;q<5;q++){
    int d = q*128+tid;
    if(d<DD) i_t[(size_t)b*DP+d] = acc[q];
  }
}

// ---------------- gi = i_t @ gru_w_ih^T + gru_b_ih ----------------
__global__ __launch_bounds__(320)
void gi_kernel(const float* __restrict__ i_t, const float* __restrict__ gwih,
               const float* __restrict__ gbih, float* __restrict__ gi){
  int b = blockIdx.x, tid = threadIdx.x; // 320
  __shared__ float it[DD];
  for(int d=tid;d<DD;d+=320) it[d]=i_t[(size_t)b*DP+d];
  __syncthreads();
  for(int n=tid;n<900;n+=320){
    const float* wr = gwih + (size_t)n*DD;
    float s=0.f;
    for(int d=0;d<DD;d++) s += wr[d]*it[d];
    gi[(size_t)b*900+n] = s + gbih[n];
  }
}

// ---------------- 3 GRU hops + dense (fused) ----------------
__global__ __launch_bounds__(320)
void hops_kernel(const float* __restrict__ gi, const float* __restrict__ gwhh,
                 const float* __restrict__ gbhh, const float* __restrict__ dw,
                 const float* __restrict__ db, float* __restrict__ out){
  int b = blockIdx.x, tid = threadIdx.x; // 320
  __shared__ float et_s[HH];
  float gir=0.f,giz=0.f,gin=0.f,bhr=0.f,bhz=0.f,bhn=0.f;
  if(tid<300){
    et_s[tid]=0.f;
    gir = gi[(size_t)b*900+tid];
    giz = gi[(size_t)b*900+300+tid];
    gin = gi[(size_t)b*900+600+tid];
    bhr = gbhh[tid]; bhz = gbhh[300+tid]; bhn = gbhh[600+tid];
  }
  __syncthreads();
  for(int hop=0;hop<3;hop++){
    float etn=0.f;
    if(tid<300){
      const float* wr = gwhh + (size_t)tid*HH;
      const float* wz = gwhh + (size_t)(300+tid)*HH;
      const float* wn = gwhh + (size_t)(600+tid)*HH;
      float ghr=bhr, ghz=bhz, ghn=bhn;
      for(int d=0;d<HH;d++){
        float e = et_s[d];
        ghr += wr[d]*e; ghz += wz[d]*e; ghn += wn[d]*e;
      }
      float r = sigf(gir+ghr);
      float z = sigf(giz+ghz);
      float n = tanhf(gin + r*ghn);
      etn = (1.f-z)*n + z*et_s[tid];
    }
    __syncthreads();
    if(tid<300) et_s[tid]=etn;
    __syncthreads();
  }
  if(tid<192){
    int p = tid/64, lane = tid%64;
    float partial = 0.f;
    for(int e=lane;e<HH;e+=64) partial += et_s[e]*dw[(size_t)p*HH+e];
    for(int off=32;off>0;off>>=1) partial += __shfl_down(partial, off);
    if(lane==0) out[(size_t)b*PP+p] = partial + db[p];
  }
}

extern "C" void kernel_launch(void* const* d_in, const int* in_sizes, int n_in,
                              void* d_out, int out_size, void* d_ws, size_t ws_size,
                              hipStream_t stream){
  (void)in_sizes; (void)n_in; (void)out_size; (void)ws_size;
  const int*   traw  = (const int*)  d_in[0];
  const int*   aidx  = (const int*)  d_in[1];
  const int*   tleft = (const int*)  d_in[2];
  const float* emb   = (const float*)d_in[3];
  const float* wihf  = (const float*)d_in[4];
  const float* whhf  = (const float*)d_in[5];
  const float* bihf  = (const float*)d_in[6];
  const float* bhhf  = (const float*)d_in[7];
  const float* wihb  = (const float*)d_in[8];
  const float* whhb  = (const float*)d_in[9];
  const float* bihb  = (const float*)d_in[10];
  const float* bhhb  = (const float*)d_in[11];
  const float* attw  = (const float*)d_in[12];
  // d_in[13] att_b unused (cancels in softmax)
  const float* gwih  = (const float*)d_in[14];
  const float* gwhh  = (const float*)d_in[15];
  const float* gbih  = (const float*)d_in[16];
  const float* gbhh  = (const float*)d_in[17];
  const float* dw    = (const float*)d_in[18];
  const float* db    = (const float*)d_in[19];
  float* out = (float*)d_out;

  char* ws = (char*)d_ws;
  size_t off = 0;
  auto alloc = [&](size_t bytes)->void*{
    void* p = ws + off;
    off += (bytes + 255) & ~(size_t)255;
    return p;
  };
  __hip_bfloat16* Xp  = (__hip_bfloat16*)alloc((size_t)2*BB*SS*G4*2);    // 157.3 MB (n'-interleaved)
  float* mem   = (float*)alloc((size_t)BB*SS*DP*4);                      // 79.7 MB
  __hip_bfloat16* Wn  = (__hip_bfloat16*)alloc((size_t)2*1280*320*2);    // 1.64 MB
  int*   lens  = (int*)  alloc(3*BB*sizeof(int));
  float* score = (float*)alloc((size_t)BB*SS*4);
  float* i_t   = (float*)alloc((size_t)BB*DP*4);
  float* gi    = (float*)alloc((size_t)BB*900*4);

  hipMemsetAsync(mem, 0, (size_t)BB*SS*DP*4, stream);

  lengths_kernel<<<BB,128,0,stream>>>(traw, tleft, aidx, lens);
  wprep_kernel<<<dim3(1280,2),320,0,stream>>>(whhf, whhb, Wn);

  xproj_mfma<<<dim3(10,256),512,0,stream>>>(traw, emb, wihf, bihf, bhhf, Xp);
  xproj_mfma<<<dim3(10,256),512,0,stream>>>(traw, emb, wihb, bihb, bhhb, Xp + (size_t)BB*SS*G4);

  lstm_self<<<32,512,0,stream>>>(Xp, Wn, mem, lens);

  loc_score_kernel<<<BB*SS,128,0,stream>>>(mem, attw, lens, score);
  softmax_it_kernel<<<BB,128,0,stream>>>(score, mem, i_t);
  gi_kernel<<<BB,320,0,stream>>>(i_t, gwih, gbih, gi);
  hops_kernel<<<BB,320,0,stream>>>(gi, gwhh, gbhh, dw, db, out);
}